// Round 9
// baseline (244.510 us; speedup 1.0000x reference)
//
#include <hip/hip_runtime.h>
#include <hip/hip_bf16.h>

typedef unsigned short ushort_t;
typedef __bf16 bf16x8 __attribute__((ext_vector_type(8)));
typedef float f32x4 __attribute__((ext_vector_type(4)));

__device__ __forceinline__ float bf2f(ushort_t u) {
    union { unsigned int i; float f; } x; x.i = ((unsigned int)u) << 16; return x.f;
}
__device__ __forceinline__ ushort_t f2bf(float f) {
    __hip_bfloat16 h = __float2bfloat16(f);
    return *(ushort_t*)&h;
}

// Fragment-packed layout (verified via R6 B-operand): element (row, k) of a
// row-major matrix stored at ((row>>4)*KT + (k>>5))*512 + (((k>>3)&3)*16 + (row&15))*8 + (k&7)
// where KT = K/32. A wave loads one (tile,kt) block as lane*8 -> 16B dwordx4.
// A-operand per-lane layout: A[m=lane&15][k=(lane>>4)*8+j]  (mirror of B).

// ---- prep ----
// blocks [0,1024): x fp32 -> xpk (packed-A, m-tile per block)
// [1024,2048): W_in -> Wpt (packed-B, scaled by Bv); [2048,3072): C -> Ct (packed-B)
__global__ void prep_fused(const float* __restrict__ x, const float* __restrict__ W_in,
                           const float* __restrict__ C, const float* __restrict__ Bv,
                           __hip_bfloat16* __restrict__ xpk, __hip_bfloat16* __restrict__ Wpt,
                           __hip_bfloat16* __restrict__ Ct) {
    int bid = blockIdx.x;
    if (bid < 1024) {
        // pack m-tile bid of x: rows 16*bid .. 16*bid+15, all K=1024
        __shared__ ushort_t sm[16 * 1032];   // stride 1032 (+16B pad) vs bank conflicts
        int tid = threadIdx.x;
        #pragma unroll
        for (int r = 0; r < 16; ++r) {
            float4 v = *(const float4*)(x + ((size_t)(bid * 16 + r)) * 1024 + tid * 4);
            ushort4 ov;
            ov.x = f2bf(v.x); ov.y = f2bf(v.y); ov.z = f2bf(v.z); ov.w = f2bf(v.w);
            *(ushort4*)&sm[r * 1032 + tid * 4] = ov;
        }
        __syncthreads();
        int lane = tid & 63;
        int quad = lane >> 4;
        int lr   = lane & 15;
        #pragma unroll
        for (int p = 0; p < 8; ++p) {
            int kt = p * 4 + (tid >> 6);
            const ushort_t* src = &sm[lr * 1032 + kt * 32 + quad * 8];
            ushort_t* dst = (ushort_t*)xpk + (((size_t)bid * 32 + kt) * 64 + lane) * 8;
            *(ushort4*)dst       = *(const ushort4*)src;
            *(ushort4*)(dst + 4) = *(const ushort4*)(src + 4);
        }
        return;
    }
    // weight packing (R6-verified): 32x32 tile transpose -> packed-B
    __shared__ float tile[32][33];
    const float* in;
    __hip_bfloat16* out;
    bool do_scale;
    int lid;
    if (bid < 2048) { lid = bid - 1024; in = W_in; out = Wpt; do_scale = true; }
    else            { lid = bid - 2048; in = C;    out = Ct;  do_scale = false; }
    int bx = (lid & 31) * 32;   // n base
    int by = (lid >> 5) * 32;   // k base
    int tx = threadIdx.x & 31, ty = threadIdx.x >> 5;
    #pragma unroll
    for (int i = 0; i < 32; i += 8)
        tile[ty + i][tx] = in[(size_t)(by + ty + i) * 1024 + bx + tx];
    __syncthreads();
    if (threadIdx.x < 128) {
        int n_local = threadIdx.x & 31;
        int quad    = threadIdx.x >> 5;
        int n = bx + n_local;
        float s = do_scale ? Bv[n] : 1.0f;
        int lr     = n & 15;
        int n_tile = n >> 4;
        int k_tile = by >> 5;
        ushort_t buf[8];
        #pragma unroll
        for (int j = 0; j < 8; ++j)
            buf[j] = f2bf(tile[quad * 8 + j][n_local] * s);
        size_t off = (((size_t)n_tile * 32 + k_tile) * 64 + quad * 16 + lr) * 8;
        ushort_t* dst = (ushort_t*)out + off;
        *(ushort4*)dst       = *(ushort4*)&buf[0];
        *(ushort4*)(dst + 4) = *(ushort4*)&buf[4];
    }
}

// ---- GEMM1 + fused scan, barrier-free K-loop ----
// A = xpk packed-A frags direct from global (rows m0-32..m0+127, 5 i-tiles);
// B = Wpt packed-B frags direct from global. No LDS, no syncthreads until epilogue.
// Epilogue: u+bias -> LDS, serial in-LDS scan, write h in packed-A layout (hpk).
__global__ __launch_bounds__(256) void gemm1_scan(
    const __hip_bfloat16* __restrict__ Apk, const __hip_bfloat16* __restrict__ Bpk,
    const float* __restrict__ b_in, const float* __restrict__ Bv,
    const float* __restrict__ logA,
    __hip_bfloat16* __restrict__ hpk, int N) {
    const int tid  = threadIdx.x;
    const int wave = tid >> 6;
    const int lane = tid & 63;
    const int quad = lane >> 4;
    const int lr   = lane & 15;
    const int wm   = wave >> 1;
    const int wn   = wave & 1;

    const int lin   = blockIdx.y * gridDim.x + blockIdx.x;
    const int xcd   = lin & 7;
    const int local = lin >> 3;
    const int m_blk = xcd * 16 + (local >> 3);
    const int n_blk = local & 7;
    const int m0 = m_blk * 128;
    const int n0 = n_blk * 128;

    __shared__ __align__(16) ushort_t sBuf[160 * 136];  // 43.5 KB (epilogue only)

    const ushort_t* Ap = (const ushort_t*)Apk;
    const ushort_t* Bp = (const ushort_t*)Bpk;

    // fragment base pointers (stride 512 ushorts per kt)
    const ushort_t* pA[5];
    const ushort_t* pB[4];
    #pragma unroll
    for (int i = 0; i < 5; ++i) {
        int mt = (m0 >> 4) - 2 + wm * 5 + i;
        if (mt < 0) mt = 0;          // m0==0 warm-up rows: garbage, skipped by scan
        pA[i] = Ap + (size_t)mt * 32 * 512 + lane * 8;
    }
    #pragma unroll
    for (int j = 0; j < 4; ++j) {
        int nt = (n0 >> 4) + wn * 4 + j;
        pB[j] = Bp + (size_t)nt * 32 * 512 + lane * 8;
    }

    f32x4 acc[5][4];
    #pragma unroll
    for (int i = 0; i < 5; ++i)
        #pragma unroll
        for (int j = 0; j < 4; ++j)
            #pragma unroll
            for (int r = 0; r < 4; ++r) acc[i][j][r] = 0.0f;

    #pragma unroll 2
    for (int kt = 0; kt < 32; ++kt) {
        bf16x8 af[5], bfr[4];
        #pragma unroll
        for (int i = 0; i < 5; ++i) af[i]  = *(const bf16x8*)(pA[i] + (size_t)kt * 512);
        #pragma unroll
        for (int j = 0; j < 4; ++j) bfr[j] = *(const bf16x8*)(pB[j] + (size_t)kt * 512);
        #pragma unroll
        for (int i = 0; i < 5; ++i)
            #pragma unroll
            for (int j = 0; j < 4; ++j)
                acc[i][j] = __builtin_amdgcn_mfma_f32_16x16x32_bf16(af[i], bfr[j], acc[i][j], 0, 0, 0);
    }

    // ---- epilogue: u+bias -> LDS (stride 136), in-LDS scan, packed-A h write ----
    __syncthreads();
    #pragma unroll
    for (int i = 0; i < 5; ++i)
        #pragma unroll
        for (int j = 0; j < 4; ++j) {
            int colL = wn * 64 + j * 16 + lr;
            float bs = b_in[n0 + colL] * Bv[n0 + colL];
            #pragma unroll
            for (int r = 0; r < 4; ++r) {
                int slot = wm * 80 + i * 16 + quad * 4 + r;   // 0..159
                sBuf[slot * 136 + colL] = f2bf(acc[i][j][r] + bs);
            }
        }
    __syncthreads();
    if (tid < 128) {
        float a = -__expf(logA[n0 + tid]);
        float h = 0.f;
        int s = ((m0 & 2047) == 0) ? 32 : 0;   // batch start: skip warm-up
        for (; s < 32; ++s)
            h = fmaf(a, h, bf2f(sBuf[s * 136 + tid]));
        #pragma unroll 4
        for (int t = 32; t < 160; ++t) {
            h = fmaf(a, h, bf2f(sBuf[t * 136 + tid]));
            sBuf[t * 136 + tid] = f2bf(h);
        }
    }
    __syncthreads();
    // write h rows m0..m0+127 in packed-A layout: 32 sub-blocks (8 m-tiles x 4 k-tiles)
    #pragma unroll
    for (int p = 0; p < 8; ++p) {
        int sb   = p * 4 + wave;       // 0..31
        int mt_l = sb >> 2;            // 0..7
        int kt_l = sb & 3;             // 0..3
        const ushort_t* src = &sBuf[(32 + mt_l * 16 + lr) * 136 + kt_l * 32 + quad * 8];
        size_t mt  = (size_t)((m0 >> 4) + mt_l);
        size_t kt2 = (size_t)((n0 >> 5) + kt_l);
        ushort_t* dst = (ushort_t*)hpk + ((mt * 32 + kt2) * 64 + lane) * 8;
        *(ushort4*)dst       = *(const ushort4*)src;
        *(ushort4*)(dst + 4) = *(const ushort4*)(src + 4);
    }
}

// ---- GEMM2, barrier-free K-loop: A = hpk packed-A, B = Ct packed-B, no LDS.
// out_f[m][n] = acc + x[m][n]*Dvec[n]  (x read fp32 directly) ----
__global__ __launch_bounds__(256) void gemm2(
    const __hip_bfloat16* __restrict__ Apk, const __hip_bfloat16* __restrict__ Bpk,
    const float* __restrict__ xres_f, const float* __restrict__ Dvec,
    float* __restrict__ out_f, int N) {
    const int tid  = threadIdx.x;
    const int wave = tid >> 6;
    const int lane = tid & 63;
    const int quad = lane >> 4;
    const int lr   = lane & 15;
    const int wm   = wave >> 1;
    const int wn   = wave & 1;

    const int lin   = blockIdx.y * gridDim.x + blockIdx.x;
    const int xcd   = lin & 7;
    const int local = lin >> 3;
    const int m_blk = xcd * 16 + (local >> 3);
    const int n_blk = local & 7;
    const int m0 = m_blk * 128;
    const int n0 = n_blk * 128;

    const ushort_t* Ap = (const ushort_t*)Apk;
    const ushort_t* Bp = (const ushort_t*)Bpk;

    const ushort_t* pA[4];
    const ushort_t* pB[4];
    #pragma unroll
    for (int i = 0; i < 4; ++i)
        pA[i] = Ap + (size_t)((m0 >> 4) + wm * 4 + i) * 32 * 512 + lane * 8;
    #pragma unroll
    for (int j = 0; j < 4; ++j)
        pB[j] = Bp + (size_t)((n0 >> 4) + wn * 4 + j) * 32 * 512 + lane * 8;

    f32x4 acc[4][4];
    #pragma unroll
    for (int i = 0; i < 4; ++i)
        #pragma unroll
        for (int j = 0; j < 4; ++j)
            #pragma unroll
            for (int r = 0; r < 4; ++r) acc[i][j][r] = 0.0f;

    #pragma unroll 2
    for (int kt = 0; kt < 32; ++kt) {
        bf16x8 af[4], bfr[4];
        #pragma unroll
        for (int i = 0; i < 4; ++i) af[i]  = *(const bf16x8*)(pA[i] + (size_t)kt * 512);
        #pragma unroll
        for (int j = 0; j < 4; ++j) bfr[j] = *(const bf16x8*)(pB[j] + (size_t)kt * 512);
        #pragma unroll
        for (int i = 0; i < 4; ++i)
            #pragma unroll
            for (int j = 0; j < 4; ++j)
                acc[i][j] = __builtin_amdgcn_mfma_f32_16x16x32_bf16(af[i], bfr[j], acc[i][j], 0, 0, 0);
    }

    // epilogue: C/D layout col=lane&15, row=quad*4+reg
    #pragma unroll
    for (int i = 0; i < 4; ++i) {
        int row = m0 + wm * 64 + i * 16 + quad * 4;
        #pragma unroll
        for (int j = 0; j < 4; ++j) {
            int col = n0 + wn * 64 + j * 16 + lr;
            float dv = Dvec[col];
            #pragma unroll
            for (int r = 0; r < 4; ++r) {
                float xv = xres_f[(size_t)(row + r) * N + col];
                out_f[(size_t)(row + r) * N + col] = acc[i][j][r] + xv * dv;
            }
        }
    }
}

extern "C" void kernel_launch(void* const* d_in, const int* in_sizes, int n_in,
                              void* d_out, int out_size, void* d_ws, size_t ws_size,
                              hipStream_t stream) {
    const float* x    = (const float*)d_in[0];
    const float* W_in = (const float*)d_in[1];
    const float* b_in = (const float*)d_in[2];
    const float* logA = (const float*)d_in[3];
    const float* Bv   = (const float*)d_in[4];
    const float* C    = (const float*)d_in[5];
    const float* Dv   = (const float*)d_in[6];
    float* out = (float*)d_out;

    const int Bsz = 8, T = 2048, d = 1024;
    const int M = Bsz * T;  // 16384

    // workspace carve (~68 MB)
    char* w = (char*)d_ws;
    __hip_bfloat16* xpk = (__hip_bfloat16*)w;                  // 32 MB packed-A
    __hip_bfloat16* Wpt = xpk + (size_t)M * d;                 //  2 MB packed-B
    __hip_bfloat16* Ct  = Wpt + (size_t)d * d;                 //  2 MB packed-B
    __hip_bfloat16* hpk = Ct + (size_t)d * d;                  // 32 MB packed-A

    prep_fused<<<3072, 256, 0, stream>>>(x, W_in, C, Bv, xpk, Wpt, Ct);

    gemm1_scan<<<dim3(8, 128), 256, 0, stream>>>(
        xpk, Wpt, b_in, Bv, logA, hpk, d);
    gemm2<<<dim3(8, 128), 256, 0, stream>>>(
        hpk, Ct, x, Dv, out, d);
}